// Round 1
// baseline (45.557 us; speedup 1.0000x reference)
//
#include <hip/hip_runtime.h>
#include <hip/hip_bf16.h>

// Problem: B=4, L=2048, E=512, D=128
//   dep[b,l,d]   = sum_e emb[b,l,e] * W[d,e]          (GEMM, B^T layout: W is [D,E])
//   dist[b,i,j]  = sq[i] + sq[j] - 2 * dep_b . dep_b  (per-batch gram + rank-1)
// d_out = dep (4*2048*128 f32) ++ distances (4*2048*2048 f32)

typedef __attribute__((ext_vector_type(8))) short  short8;   // 8 bf16 (4 VGPRs)
typedef __attribute__((ext_vector_type(4))) float  floatx4;  // MFMA C/D frag

#define B_  4
#define L_  2048
#define E_  512
#define D_  128
#define M_  (B_*L_)   // 8192

__device__ __forceinline__ unsigned short f2bf(float x) {
    union { float f; unsigned u; } v; v.f = x;
    unsigned r = v.u + 0x7FFF + ((v.u >> 16) & 1);   // round-to-nearest-even
    return (unsigned short)(r >> 16);
}

// ---------------- Kernel A: dep = emb @ W^T  (M=8192, N=128, K=512) ----------
// Block: 256 thr (4 waves, 2x2), tile 128(M) x 128(N). K staged 32 at a time.
__global__ __launch_bounds__(256)
void kA(const float* __restrict__ emb, const float* __restrict__ W,
        float* __restrict__ dep_out, unsigned short* __restrict__ dep_b16)
{
    // +8 bf16 pad -> row stride 80B = 5*16B (odd multiple of 16B): conflict-free b128
    __shared__ __align__(16) unsigned short As[128][40];
    __shared__ __align__(16) unsigned short Bs[128][40];

    const int tid  = threadIdx.x;
    const int lane = tid & 63;
    const int wave = tid >> 6;
    const int wr = wave >> 1, wc = wave & 1;      // 2x2 wave grid, 64x64 per wave
    const int l15 = lane & 15, lg = lane >> 4;
    const long m0 = (long)blockIdx.x * 128;

    floatx4 acc[4][4];
    #pragma unroll
    for (int i = 0; i < 4; ++i)
        #pragma unroll
        for (int j = 0; j < 4; ++j)
            acc[i][j] = (floatx4){0.f, 0.f, 0.f, 0.f};

    for (int k0 = 0; k0 < E_; k0 += 32) {
        // stage 128x32 of emb and of W, f32 -> bf16
        #pragma unroll
        for (int jj = 0; jj < 4; ++jj) {
            int chunk = tid + 256 * jj;           // 0..1023
            int row = chunk >> 3, c4 = chunk & 7; // 8 float4 per 32-wide row
            float4 va = *reinterpret_cast<const float4*>(emb + (m0 + row) * E_ + k0 + c4 * 4);
            ushort4 ua;
            ua.x = f2bf(va.x); ua.y = f2bf(va.y); ua.z = f2bf(va.z); ua.w = f2bf(va.w);
            *reinterpret_cast<ushort4*>(&As[row][c4 * 4]) = ua;
            float4 vb = *reinterpret_cast<const float4*>(W + row * E_ + k0 + c4 * 4);
            ushort4 ub;
            ub.x = f2bf(vb.x); ub.y = f2bf(vb.y); ub.z = f2bf(vb.z); ub.w = f2bf(vb.w);
            *reinterpret_cast<ushort4*>(&Bs[row][c4 * 4]) = ub;
        }
        __syncthreads();

        short8 af[4], bfr[4];
        #pragma unroll
        for (int mi = 0; mi < 4; ++mi)
            af[mi] = *reinterpret_cast<const short8*>(&As[wr * 64 + mi * 16 + l15][lg * 8]);
        #pragma unroll
        for (int ni = 0; ni < 4; ++ni)
            bfr[ni] = *reinterpret_cast<const short8*>(&Bs[wc * 64 + ni * 16 + l15][lg * 8]);
        #pragma unroll
        for (int mi = 0; mi < 4; ++mi)
            #pragma unroll
            for (int ni = 0; ni < 4; ++ni)
                acc[mi][ni] = __builtin_amdgcn_mfma_f32_16x16x32_bf16(
                    af[mi], bfr[ni], acc[mi][ni], 0, 0, 0);
        __syncthreads();
    }

    // epilogue: C/D layout col=lane&15, row=(lane>>4)*4+j  [m89-verified]
    #pragma unroll
    for (int mi = 0; mi < 4; ++mi) {
        #pragma unroll
        for (int j = 0; j < 4; ++j) {
            long row = m0 + wr * 64 + mi * 16 + lg * 4 + j;
            #pragma unroll
            for (int ni = 0; ni < 4; ++ni) {
                int col = wc * 64 + ni * 16 + l15;
                float v = acc[mi][ni][j];
                dep_out[row * D_ + col] = v;
                dep_b16[row * D_ + col] = f2bf(v);
            }
        }
    }
}

// ---------------- Kernel SQ: sq[row] = sum_d dep_b16[row][d]^2 ---------------
__global__ __launch_bounds__(256)
void kSQ(const unsigned short* __restrict__ dep_b16, float* __restrict__ sq)
{
    int row  = blockIdx.x * 4 + (threadIdx.x >> 6);
    int lane = threadIdx.x & 63;
    unsigned v = *reinterpret_cast<const unsigned*>(dep_b16 + (long)row * D_ + lane * 2);
    union { unsigned u; float f; } a, b;
    a.u = v << 16; b.u = v & 0xFFFF0000u;
    float s = a.f * a.f + b.f * b.f;
    #pragma unroll
    for (int off = 32; off; off >>= 1) s += __shfl_down(s, off);
    if (lane == 0) sq[row] = s;
}

// ---------------- Kernel B: dist = sq_i + sq_j - 2 * dep dep^T ---------------
// Block: 256 thr (4 waves, 2x2), tile 128(i) x 128(j), full K=128 staged once.
__global__ __launch_bounds__(256)
void kB(const unsigned short* __restrict__ dep_b16, const float* __restrict__ sq,
        float* __restrict__ dist)
{
    // +8 bf16 pad -> row stride 272B = 17*16B: conflict-free b128
    __shared__ __align__(16) unsigned short Is[128][136];
    __shared__ __align__(16) unsigned short Js[128][136];

    const int tid  = threadIdx.x;
    const int lane = tid & 63;
    const int wave = tid >> 6;
    const int wr = wave >> 1, wc = wave & 1;
    const int l15 = lane & 15, lg = lane >> 4;
    const int b  = blockIdx.z;
    const int i0 = blockIdx.y * 128;
    const int j0 = blockIdx.x * 128;
    const unsigned short* depb = dep_b16 + (long)b * L_ * D_;

    #pragma unroll
    for (int jj = 0; jj < 8; ++jj) {
        int chunk = tid + 256 * jj;               // 0..2047
        int row = chunk >> 4, c8 = chunk & 15;    // 16 x 16B chunks per 128-wide row
        short8 vi = *reinterpret_cast<const short8*>(depb + (long)(i0 + row) * D_ + c8 * 8);
        *reinterpret_cast<short8*>(&Is[row][c8 * 8]) = vi;
        short8 vj = *reinterpret_cast<const short8*>(depb + (long)(j0 + row) * D_ + c8 * 8);
        *reinterpret_cast<short8*>(&Js[row][c8 * 8]) = vj;
    }
    __syncthreads();

    floatx4 acc[4][4];
    #pragma unroll
    for (int i = 0; i < 4; ++i)
        #pragma unroll
        for (int j = 0; j < 4; ++j)
            acc[i][j] = (floatx4){0.f, 0.f, 0.f, 0.f};

    #pragma unroll
    for (int kk = 0; kk < 4; ++kk) {
        short8 af[4], bfr[4];
        #pragma unroll
        for (int mi = 0; mi < 4; ++mi)
            af[mi] = *reinterpret_cast<const short8*>(&Is[wr * 64 + mi * 16 + l15][kk * 32 + lg * 8]);
        #pragma unroll
        for (int ni = 0; ni < 4; ++ni)
            bfr[ni] = *reinterpret_cast<const short8*>(&Js[wc * 64 + ni * 16 + l15][kk * 32 + lg * 8]);
        #pragma unroll
        for (int mi = 0; mi < 4; ++mi)
            #pragma unroll
            for (int ni = 0; ni < 4; ++ni)
                acc[mi][ni] = __builtin_amdgcn_mfma_f32_16x16x32_bf16(
                    af[mi], bfr[ni], acc[mi][ni], 0, 0, 0);
    }

    const float* sqb = sq + b * L_;
    float sqc[4];
    #pragma unroll
    for (int ni = 0; ni < 4; ++ni)
        sqc[ni] = sqb[j0 + wc * 64 + ni * 16 + l15];

    float* db = dist + (long)b * L_ * L_;
    #pragma unroll
    for (int mi = 0; mi < 4; ++mi) {
        #pragma unroll
        for (int j = 0; j < 4; ++j) {
            int row = i0 + wr * 64 + mi * 16 + lg * 4 + j;
            float sr = sqb[row];
            #pragma unroll
            for (int ni = 0; ni < 4; ++ni) {
                int col = j0 + wc * 64 + ni * 16 + l15;
                db[(long)row * L_ + col] = sr + sqc[ni] - 2.0f * acc[mi][ni][j];
            }
        }
    }
}

extern "C" void kernel_launch(void* const* d_in, const int* in_sizes, int n_in,
                              void* d_out, int out_size, void* d_ws, size_t ws_size,
                              hipStream_t stream)
{
    const float* emb = (const float*)d_in[0];   // [B,L,E] f32
    const float* W   = (const float*)d_in[1];   // [D,E]   f32

    float* dep_out = (float*)d_out;                       // [B*L, D]
    float* dist    = dep_out + (size_t)M_ * D_;           // [B, L, L]

    unsigned short* dep_b16 = (unsigned short*)d_ws;      // 2 MB
    float* sq = (float*)((char*)d_ws + (size_t)M_ * D_ * sizeof(unsigned short)); // 32 KB

    hipLaunchKernelGGL(kA,  dim3(M_ / 128), dim3(256), 0, stream, emb, W, dep_out, dep_b16);
    hipLaunchKernelGGL(kSQ, dim3(M_ / 4),   dim3(256), 0, stream, dep_b16, sq);
    hipLaunchKernelGGL(kB,  dim3(L_ / 128, L_ / 128, B_), dim3(256), 0, stream,
                       dep_b16, sq, dist);
}